// Round 8
// baseline (97.630 us; speedup 1.0000x reference)
//
#include <hip/hip_runtime.h>

typedef __bf16 bf16;
typedef __attribute__((ext_vector_type(8))) __bf16 bf16x8;
typedef __attribute__((ext_vector_type(4))) __bf16 bf16x4;
typedef __attribute__((ext_vector_type(4))) float f32x4;
typedef __attribute__((ext_vector_type(16))) float f32x16;
typedef __attribute__((ext_vector_type(4))) unsigned u32x4;

#define MFMA16(a, b, c) __builtin_amdgcn_mfma_f32_16x16x32_bf16(a, b, c, 0, 0, 0)
#define MFMA32(a, b, c) __builtin_amdgcn_mfma_f32_32x32x16_bf16(a, b, c, 0, 0, 0)

__device__ inline void gload_lds16(const void* g, void* l) {
  __builtin_amdgcn_global_load_lds(
      (const __attribute__((address_space(1))) void*)g,
      (__attribute__((address_space(3))) void*)l, 16, 0, 0);
}

__device__ inline unsigned packbf(float a, float b) {
  unsigned short x = __builtin_bit_cast(unsigned short, (bf16)a);
  unsigned short y = __builtin_bit_cast(unsigned short, (bf16)b);
  return (unsigned)x | ((unsigned)y << 16);
}

// ---------------------------------------------------------------------------
// prep: Xbf = bf16(concat(prev_x, x)); Wqkvt[768][256], Woutt[256][256] = W^T
// ---------------------------------------------------------------------------
__global__ __launch_bounds__(256) void prep_kernel(
    const float* __restrict__ x, const float* __restrict__ px,
    const float* __restrict__ Wqkv, const float* __restrict__ Wout,
    bf16* __restrict__ Xbf, bf16* __restrict__ Wqkvt, bf16* __restrict__ Woutt)
{
  int tid = blockIdx.x * 256 + threadIdx.x;
  int nth = gridDim.x * 256;
  for (int i = tid; i < (4 * 4096 * 256) / 4; i += nth) {
    int e = i << 2;
    int b = e >> 20;
    int r = e & 1048575;
    const float* src = (r < 524288) ? (px + (b << 19) + r)
                                    : (x + (b << 19) + (r - 524288));
    float4 f = *(const float4*)src;
    bf16x4 o = { (bf16)f.x, (bf16)f.y, (bf16)f.z, (bf16)f.w };
    *(bf16x4*)(Xbf + e) = o;
  }
  for (int i = tid; i < 768 * 256; i += nth) {
    int n = i >> 8, k = i & 255;
    Wqkvt[i] = (bf16)Wqkv[k * 768 + n];
  }
  for (int i = tid; i < 256 * 256; i += nth) {
    int n = i >> 8, k = i & 255;
    Woutt[i] = (bf16)Wout[k * 256 + n];
  }
}

// ---------------------------------------------------------------------------
// GEMM: C[M][N] = A[M][256] @ Wt[N][256]^T + bias
// MODE 0: writes Q/K/V in MFMA-FRAGMENT order for the 32x32x16 attention:
//   Qp  [qg][ks 16][lane 64][e 8]           (q = qg*32 + (lane&31), prescaled)
//   KVp [b*128+T][ K: ks*512 | V: 8192 + (s*8+dg)*512 ][lane*8 + e]
// MODE 1: A = attn-out bf16 (M=8192) -> f32 d_out
// ---------------------------------------------------------------------------
template<int MODE>
__global__ __launch_bounds__(256) void gemm_kernel(
    const bf16* __restrict__ A, const bf16* __restrict__ Wt,
    const float* __restrict__ bias,
    bf16* __restrict__ Qo, bf16* __restrict__ KVo, float* __restrict__ Fo)
{
  const int bm = blockIdx.x * 64;
  const int n0 = blockIdx.y * 128;
  const int tid = threadIdx.x;
  const int lane = tid & 63, w = tid >> 6;
  const int l15 = lane & 15, lg = lane >> 4;

  alignas(16) __shared__ bf16 Alds[64 * 32];
  alignas(16) __shared__ bf16 Wlds[128 * 32];

  f32x4 acc[8] = {};

  for (int k0 = 0; k0 < 256; k0 += 32) {
    __syncthreads();
    {
      int c = tid;
      int row = c >> 2, kc = (c & 3) << 3;
      bf16x8 v = *(const bf16x8*)(A + (size_t)(bm + row) * 256 + k0 + kc);
      *(bf16x8*)((char*)Alds + ((c << 4) ^ (((row >> 1) & 3) << 4))) = v;
    }
    #pragma unroll
    for (int it = 0; it < 2; it++) {
      int c = it * 256 + tid;
      int row = c >> 2, kc = (c & 3) << 3;
      bf16x8 v = *(const bf16x8*)(Wt + (size_t)(n0 + row) * 256 + k0 + kc);
      *(bf16x8*)((char*)Wlds + ((c << 4) ^ (((row >> 1) & 3) << 4))) = v;
    }
    __syncthreads();
    const int arow = w * 16 + l15;
    bf16x8 afr = *(const bf16x8*)((char*)Alds +
        (((arow << 6) + (lg << 4)) ^ (((arow >> 1) & 3) << 4)));
    #pragma unroll
    for (int nt = 0; nt < 8; nt++) {
      const int wrow = nt * 16 + l15;
      bf16x8 bfr = *(const bf16x8*)((char*)Wlds +
          (((wrow << 6) + (lg << 4)) ^ (((wrow >> 1) & 3) << 4)));
      acc[nt] = MFMA16(afr, bfr, acc[nt]);
    }
  }

  #pragma unroll
  for (int nt = 0; nt < 8; nt++) {
    const int n = n0 + nt * 16 + l15;
    const float bv = bias[n];
    const int m0 = bm + w * 16 + lg * 4;
    if (MODE == 0) {
      const int bq = m0 >> 12;
      const int s = m0 & 4095;
      if (n < 256) {
        if (s >= 2048) {
          const int ks = n >> 4, h2 = (n >> 3) & 1, e = n & 7;
          #pragma unroll
          for (int r = 0; r < 4; r++) {
            const int qrow = bq * 2048 + (s - 2048) + r;
            Qo[(size_t)(qrow >> 5) * 8192 + ks * 512 +
               ((qrow & 31) + 32 * h2) * 8 + e] =
                (bf16)((acc[nt][r] + bv) * 0.0625f);
          }
        }
      } else if (n < 512) {
        const int d = n - 256;
        const int ks = d >> 4, h2 = (d >> 3) & 1, e = d & 7;
        const size_t tb = (size_t)(bq * 128 + (s >> 5)) * 16384;
        #pragma unroll
        for (int r = 0; r < 4; r++)
          KVo[tb + ks * 512 + (((s & 31) + r) + 32 * h2) * 8 + e] =
              (bf16)(acc[nt][r] + bv);
      } else {
        const int d = n - 512;
        const int kv32 = s & 31;
        const int sidx = kv32 >> 4, h2 = (kv32 >> 3) & 1, e0 = kv32 & 7;
        bf16x4 st = { (bf16)(acc[nt][0] + bv), (bf16)(acc[nt][1] + bv),
                      (bf16)(acc[nt][2] + bv), (bf16)(acc[nt][3] + bv) };
        *(bf16x4*)(KVo + (size_t)(bq * 128 + (s >> 5)) * 16384 + 8192 +
                   (sidx * 8 + (d >> 5)) * 512 + ((d & 31) + 32 * h2) * 8 + e0) = st;
      }
    } else {
      #pragma unroll
      for (int r = 0; r < 4; r++)
        Fo[(size_t)((m0 + r) * 256 + n)] = acc[nt][r] + bv;
    }
  }
}

// ---------------------------------------------------------------------------
// flash attention: 32x32x16 MFMA, q=32/wave, 4 waves = 128 q/block.
// KV-split 8 -> 512 blocks. Fragment-ordered global K/V, global_load_lds.
// Software-pipelined one tile ahead: QK(t+1) issues onto the MFMA pipe,
// then softmax(t) runs on the VALU pipe concurrently, then PV(t).
// Buffer lifetimes: K ring-3 (staged 2 ahead), V ring-2 (staged 1 ahead).
// ---------------------------------------------------------------------------
__global__ __launch_bounds__(256, 2) void attn_kernel(
    const bf16* __restrict__ Qp, const bf16* __restrict__ KVp,
    bf16* __restrict__ Opart, float* __restrict__ ml)
{
  const int id = blockIdx.x;
  const int c = id & 7;            // kv chunk -> XCD affinity (id%8)
  const int b = (id >> 3) & 3;     // batch
  const int qb = id >> 5;          // q block 0..15
  const int tid = threadIdx.x;
  const int lane = tid & 63, w = tid >> 6;
  const int l31 = lane & 31, hi = lane >> 5;

  __shared__ bf16 Kb[3][8192];     // K frag tiles, ring-3 (16 KB each)
  __shared__ bf16 Vb[2][8192];     // V frag tiles, ring-2

  // Q fragments (fragment-ordered global, lane-contiguous 1KB loads)
  const int qg = b * 64 + qb * 4 + w;
  const bf16* qbase = Qp + (size_t)qg * 8192 + lane * 8;
  bf16x8 qf[16];
  #pragma unroll
  for (int ks = 0; ks < 16; ks++)
    qf[ks] = *(const bf16x8*)(qbase + ks * 512);

  const char* kvtile0 = (const char*)(KVp + (size_t)(b * 128 + c * 16) * 16384);

  auto stage_K = [&](int t, int ring) {
    const char* g = kvtile0 + (size_t)t * 32768 + w * 4096 + lane * 16;
    char* l = (char*)&Kb[ring][0] + w * 4096;
    #pragma unroll
    for (int j = 0; j < 4; j++)
      gload_lds16(g + j * 1024, l + j * 1024);
  };
  auto stage_V = [&](int t, int ring) {
    const char* g = kvtile0 + (size_t)t * 32768 + 16384 + w * 4096 + lane * 16;
    char* l = (char*)&Vb[ring][0] + w * 4096;
    #pragma unroll
    for (int j = 0; j < 4; j++)
      gload_lds16(g + j * 1024, l + j * 1024);
  };

  auto qk = [&](const bf16* kbuf) {
    f32x16 p = {};
    __builtin_amdgcn_s_setprio(1);
    #pragma unroll
    for (int ks = 0; ks < 16; ks++) {
      bf16x8 kf = *(const bf16x8*)(kbuf + ks * 512 + lane * 8);
      p = MFMA32(kf, qf[ks], p);
    }
    __builtin_amdgcn_s_setprio(0);
    return p;
  };

  stage_K(0, 0);
  stage_V(0, 0);
  stage_K(1, 1);

  f32x16 o[8] = {};                // O^T[d][q]: q = l31, d = dg*32+8*(r>>2)+4*hi+(r&3)
  f32x16 pA;
  float m_run = -1e30f, l_run = 0.f;

  #pragma unroll
  for (int t = 0; t < 16; t++) {
    __syncthreads();               // stage(t) [and t+1 K] landed; rings safe
    if (t + 2 < 16) stage_K(t + 2, (t + 2) % 3);
    if (t + 1 < 16) stage_V(t + 1, (t + 1) & 1);

    if (t == 0) pA = qk(&Kb[0][0]);
    f32x16 pN = {};
    if (t + 1 < 16) pN = qk(&Kb[(t + 1) % 3][0]);  // fills MFMA pipe during softmax(t)

    // --- softmax(tile t) on pA (VALU pipe, overlaps pN's MFMAs) ---
    f32x16 p = pA;
    float m0 = fmaxf(p[0], p[1]),   m1 = fmaxf(p[2], p[3]);
    float m2 = fmaxf(p[4], p[5]),   m3 = fmaxf(p[6], p[7]);
    float m4 = fmaxf(p[8], p[9]),   m5 = fmaxf(p[10], p[11]);
    float m6 = fmaxf(p[12], p[13]), m7 = fmaxf(p[14], p[15]);
    m0 = fmaxf(m0, m1); m2 = fmaxf(m2, m3); m4 = fmaxf(m4, m5); m6 = fmaxf(m6, m7);
    float mt = fmaxf(fmaxf(m0, m2), fmaxf(m4, m6));
    mt = fmaxf(mt, __shfl_xor(mt, 32));
    if (!__all(mt <= m_run + 8.f)) {   // defer-max (T13)
      const float m_new = fmaxf(m_run, mt);
      const float alpha = __expf(m_run - m_new);
      l_run *= alpha;
      #pragma unroll
      for (int i = 0; i < 8; i++)
        #pragma unroll
        for (int j = 0; j < 16; j++) o[i][j] *= alpha;
      m_run = m_new;
    }
    #pragma unroll
    for (int i = 0; i < 16; i++) p[i] = __expf(p[i] - m_run);
    float s0 = (p[0] + p[1]) + (p[2] + p[3]);
    float s1 = (p[4] + p[5]) + (p[6] + p[7]);
    float s2 = (p[8] + p[9]) + (p[10] + p[11]);
    float s3 = (p[12] + p[13]) + (p[14] + p[15]);
    float ps = (s0 + s1) + (s2 + s3);
    ps += __shfl_xor(ps, 32);
    l_run += ps;

    // P -> B-frags. Lane (q,hi) holds kv j at word u[i]:
    //   hi=0: u0..u7 = kv(0,1)(2,3)(8,9)(10,11)(16,17)(18,19)(24,25)(26,27)
    //   hi=1: u0..u7 = kv(4,5)(6,7)(12,13)(14,15)(20,21)(22,23)(28,29)(30,31)
    // B-frag word j of pf0 needs kv(8*hi+2j, 8*hi+2j+1); pf1: +16.
    unsigned u[8], xp[8];
    #pragma unroll
    for (int i = 0; i < 8; i++) u[i] = packbf(p[2 * i], p[2 * i + 1]);
    #pragma unroll
    for (int i = 0; i < 8; i++)
      xp[i] = (unsigned)__shfl_xor((int)u[i], 32);
    const u32x4 w0 = hi ? (u32x4){xp[2], xp[3], u[2], u[3]}
                        : (u32x4){u[0], u[1], xp[0], xp[1]};
    const u32x4 w1 = hi ? (u32x4){xp[6], xp[7], u[6], u[7]}
                        : (u32x4){u[4], u[5], xp[4], xp[5]};
    const bf16x8 pf0 = __builtin_bit_cast(bf16x8, w0);
    const bf16x8 pf1 = __builtin_bit_cast(bf16x8, w1);

    // O^T += V^T . P (queues behind pN's MFMAs on the matrix pipe)
    const bf16* vbuf = &Vb[t & 1][0];
    __builtin_amdgcn_s_setprio(1);
    #pragma unroll
    for (int dg = 0; dg < 8; dg++) {
      bf16x8 v0 = *(const bf16x8*)(vbuf + dg * 512 + lane * 8);
      o[dg] = MFMA32(v0, pf0, o[dg]);
      bf16x8 v1 = *(const bf16x8*)(vbuf + (8 + dg) * 512 + lane * 8);
      o[dg] = MFMA32(v1, pf1, o[dg]);
    }
    __builtin_amdgcn_s_setprio(0);

    pA = pN;
  }

  const int q = b * 2048 + qb * 128 + w * 32 + l31;
  bf16* ob = Opart + ((size_t)c * 8192 + q) * 256;
  #pragma unroll
  for (int dg = 0; dg < 8; dg++) {
    #pragma unroll
    for (int r4 = 0; r4 < 4; r4++) {
      const int d = dg * 32 + r4 * 8 + hi * 4;
      bf16x4 st = { (bf16)o[dg][r4 * 4 + 0], (bf16)o[dg][r4 * 4 + 1],
                    (bf16)o[dg][r4 * 4 + 2], (bf16)o[dg][r4 * 4 + 3] };
      *(bf16x4*)(ob + d) = st;
    }
  }
  if (hi == 0) {
    float2 v = { m_run, l_run };
    *(float2*)(ml + ((size_t)c * 8192 + q) * 2) = v;
  }
}

// ---------------------------------------------------------------------------
// combine the 8 KV-split partials
// ---------------------------------------------------------------------------
__global__ __launch_bounds__(256) void combine_kernel(
    const bf16* __restrict__ Opart, const float* __restrict__ ml,
    bf16* __restrict__ AO)
{
  const int id = blockIdx.x * 256 + threadIdx.x;   // q*32 + dchunk
  const int q = id >> 5, dc = (id & 31) << 3;
  float ms[8], ls[8], M = -1e30f;
  #pragma unroll
  for (int s = 0; s < 8; s++) {
    float2 v = *(const float2*)(ml + ((size_t)s * 8192 + q) * 2);
    ms[s] = v.x; ls[s] = v.y;
    M = fmaxf(M, v.x);
  }
  float L = 0.f;
  float acc[8] = {};
  #pragma unroll
  for (int s = 0; s < 8; s++) {
    const float wgt = __expf(ms[s] - M);
    L += ls[s] * wgt;
    bf16x8 v = *(const bf16x8*)(Opart + ((size_t)s * 8192 + q) * 256 + dc);
    #pragma unroll
    for (int j = 0; j < 8; j++) acc[j] += wgt * (float)v[j];
  }
  const float inv = 1.f / L;
  bf16x8 st;
  #pragma unroll
  for (int j = 0; j < 8; j++) st[j] = (bf16)(acc[j] * inv);
  *(bf16x8*)(AO + (size_t)q * 256 + dc) = st;
}

// ---------------------------------------------------------------------------
extern "C" void kernel_launch(void* const* d_in, const int* in_sizes, int n_in,
                              void* d_out, int out_size, void* d_ws, size_t ws_size,
                              hipStream_t stream) {
  const float* x    = (const float*)d_in[0];
  const float* px   = (const float*)d_in[1];
  const float* Wqkv = (const float*)d_in[2];
  const float* bqkv = (const float*)d_in[3];
  const float* Wout = (const float*)d_in[4];
  const float* bout = (const float*)d_in[5];
  float* out = (float*)d_out;

  char* ws = (char*)d_ws;
  bf16* Qp    = (bf16*)(ws);                    //  4 MB frag-ordered Q (*1/16)
  bf16* KVp   = (bf16*)(ws + 4194304);          // 16 MB frag-ordered K|V tiles
  bf16* Woutt = (bf16*)(ws + 20971520);         // 128 KB
  bf16* Wqkvt = (bf16*)(ws + 21102592);         // 384 KB
  float* ml   = (float*)(ws + 21495808);        // 512 KB [8][8192][2]
  bf16* Xbf   = (bf16*)(ws + 22020096);         //  8 MB (dead after gemm0)
  bf16* Opart = (bf16*)(ws + 22020096);         // 32 MB [8][8192][256] (reuses Xbf)
  bf16* AObf  = (bf16*)(ws);                    //  4 MB (reuses Qp after attn)

  prep_kernel<<<dim3(512), dim3(256), 0, stream>>>(x, px, Wqkv, Wout,
                                                   Xbf, Wqkvt, Woutt);
  gemm_kernel<0><<<dim3(256, 6), dim3(256), 0, stream>>>(
      Xbf, Wqkvt, bqkv, Qp, KVp, nullptr);
  attn_kernel<<<dim3(512), dim3(256), 0, stream>>>(Qp, KVp, Opart, ml);
  combine_kernel<<<dim3(1024), dim3(256), 0, stream>>>(Opart, ml, AObf);
  gemm_kernel<1><<<dim3(128, 2), dim3(256), 0, stream>>>(
      AObf, Woutt, bout, nullptr, nullptr, out);
}